// Round 3
// baseline (90.037 us; speedup 1.0000x reference)
//
#include <hip/hip_runtime.h>
#include <hip/hip_cooperative_groups.h>

namespace cg = cooperative_groups;

#define H 2048
#define CH 19

__device__ __forceinline__ float wred(float s) {
    #pragma unroll
    for (int off = 32; off; off >>= 1) s += __shfl_down(s, off, 64);
    return s;
}

__device__ __forceinline__ float dot_row(const float4* __restrict__ row,
                                         const float4* __restrict__ x, int lane) {
    float s = 0.f;
    #pragma unroll
    for (int j = 0; j < 8; ++j) {
        float4 w = row[lane + j * 64];
        float4 v = x[lane + j * 64];
        s += w.x * v.x + w.y * v.y + w.z * v.z + w.w * v.w;
    }
    return s;
}

// Persistent cooperative kernel: 256-thr blocks (4 waves), wave -> unit(s).
// Zero initial state => w_hh dead, f-gate dead. Layer-1 rows for the wave's
// first unit are prefetched into 96 VGPRs before layer 0 so the two 50 MB
// HBM streams overlap across the grid.sync().
__global__ __launch_bounds__(256, 2) void fused_kernel(
    const int* __restrict__ idxp, const int* __restrict__ taskp,
    const float* __restrict__ emb,
    const float* __restrict__ w0, const float* __restrict__ bi0, const float* __restrict__ bh0,
    const float* __restrict__ w1, const float* __restrict__ bi1, const float* __restrict__ bh1,
    const float* __restrict__ wc, const float* __restrict__ bc,
    float* __restrict__ out, float* __restrict__ ws)
{
    cg::grid_group grid = cg::this_grid();
    const int lane = threadIdx.x & 63;
    const int gw   = blockIdx.x * 4 + (threadIdx.x >> 6); // global wave id
    const int W    = gridDim.x * 4;                        // total waves
    float* h0 = ws;
    float* h1 = ws + H;

    const float4* xv = (const float4*)(emb + (size_t)idxp[0] * H);

    // ---- prefetch layer-1 rows for first assigned unit (overlaps layer-0 stream) ----
    const int u0 = gw;  // grid is capped at 512 blocks -> gw < 2048 always
    float4 p_i[8], p_g[8], p_o[8];
    {
        const float4* a = (const float4*)(w1 + (size_t)u0 * H);
        const float4* b = (const float4*)(w1 + (size_t)(2 * H + u0) * H);
        const float4* c = (const float4*)(w1 + (size_t)(3 * H + u0) * H);
        #pragma unroll
        for (int j = 0; j < 8; ++j) p_i[j] = a[lane + j * 64];
        #pragma unroll
        for (int j = 0; j < 8; ++j) p_g[j] = b[lane + j * 64];
        #pragma unroll
        for (int j = 0; j < 8; ++j) p_o[j] = c[lane + j * 64];
    }

    // ---- layer 0 ----
    for (int u = gw; u < H; u += W) {
        float ai = wred(dot_row((const float4*)(w0 + (size_t)u * H),           xv, lane));
        float ag = wred(dot_row((const float4*)(w0 + (size_t)(2 * H + u) * H), xv, lane));
        float ao = wred(dot_row((const float4*)(w0 + (size_t)(3 * H + u) * H), xv, lane));
        if (lane == 0) {
            float gi = ai + bi0[u]         + bh0[u];
            float gg = ag + bi0[2 * H + u] + bh0[2 * H + u];
            float go = ao + bi0[3 * H + u] + bh0[3 * H + u];
            float si  = 1.f / (1.f + expf(-gi));
            float so_ = 1.f / (1.f + expf(-go));
            h0[u] = so_ * tanhf(si * tanhf(gg));
        }
    }
    grid.sync();

    // ---- layer 1 (first unit from prefetched registers) ----
    const float4* h0v = (const float4*)h0;
    for (int u = gw; u < H; u += W) {
        float ai, ag, ao;
        if (u == u0) {
            ai = ag = ao = 0.f;
            #pragma unroll
            for (int j = 0; j < 8; ++j) {
                float4 hv = h0v[lane + j * 64];
                ai += p_i[j].x * hv.x + p_i[j].y * hv.y + p_i[j].z * hv.z + p_i[j].w * hv.w;
                ag += p_g[j].x * hv.x + p_g[j].y * hv.y + p_g[j].z * hv.z + p_g[j].w * hv.w;
                ao += p_o[j].x * hv.x + p_o[j].y * hv.y + p_o[j].z * hv.z + p_o[j].w * hv.w;
            }
        } else {
            ai = dot_row((const float4*)(w1 + (size_t)u * H),           h0v, lane);
            ag = dot_row((const float4*)(w1 + (size_t)(2 * H + u) * H), h0v, lane);
            ao = dot_row((const float4*)(w1 + (size_t)(3 * H + u) * H), h0v, lane);
        }
        ai = wred(ai); ag = wred(ag); ao = wred(ao);
        if (lane == 0) {
            float gi = ai + bi1[u]         + bh1[u];
            float gg = ag + bi1[2 * H + u] + bh1[2 * H + u];
            float go = ao + bi1[3 * H + u] + bh1[3 * H + u];
            float si  = 1.f / (1.f + expf(-gi));
            float so_ = 1.f / (1.f + expf(-go));
            h1[u] = so_ * tanhf(si * tanhf(gg));
        }
    }
    grid.sync();

    // ---- logits + prefix mask ----
    const float4* h1v = (const float4*)h1;
    for (int r = gw; r < CH; r += W) {
        float s = wred(dot_row((const float4*)(wc + (size_t)r * H), h1v, lane));
        if (lane == 0) {
            int task = taskp[0];
            out[r] = (r < 1 + task) ? (s + bc[r]) : -1e9f;
        }
    }
}

// ---------------- fallback (proven R1 path) ----------------
__global__ __launch_bounds__(192) void lstm_layer_kernel(
    const float* __restrict__ w_ih, const float* __restrict__ b_ih,
    const float* __restrict__ b_hh, const float* __restrict__ x_base,
    const int* __restrict__ idx_ptr, float* __restrict__ h_out)
{
    const int unit = blockIdx.x;
    const int wave = threadIdx.x >> 6;
    const int lane = threadIdx.x & 63;
    const int gate_off = (wave == 0) ? 0 : (wave == 1 ? 2 * H : 3 * H);
    const int row = gate_off + unit;
    const float* x = x_base + (idx_ptr ? (size_t)idx_ptr[0] * H : 0);
    float sum = wred(dot_row((const float4*)(w_ih + (size_t)row * H), (const float4*)x, lane));
    __shared__ float g_lds[3];
    if (lane == 0) g_lds[wave] = sum + b_ih[row] + b_hh[row];
    __syncthreads();
    if (threadIdx.x == 0) {
        float si = 1.f / (1.f + expf(-g_lds[0]));
        float so = 1.f / (1.f + expf(-g_lds[2]));
        h_out[unit] = so * tanhf(si * tanhf(g_lds[1]));
    }
}

__global__ __launch_bounds__(64) void logits_kernel(
    const float* __restrict__ wc, const float* __restrict__ bc,
    const float* __restrict__ h, const int* __restrict__ taskp,
    float* __restrict__ out)
{
    const int r = blockIdx.x;
    const int lane = threadIdx.x;
    float s = wred(dot_row((const float4*)(wc + (size_t)r * H), (const float4*)h, lane));
    if (lane == 0) {
        int task = taskp[0];
        out[r] = (r < 1 + task) ? (s + bc[r]) : -1e9f;
    }
}

extern "C" void kernel_launch(void* const* d_in, const int* in_sizes, int n_in,
                              void* d_out, int out_size, void* d_ws, size_t ws_size,
                              hipStream_t stream) {
    const int*   idx  = (const int*)d_in[0];
    const int*   task = (const int*)d_in[1];
    const float* emb  = (const float*)d_in[2];
    const float* w0   = (const float*)d_in[3];
    // d_in[4] = w_hh_0: dead (h == 0)
    const float* bi0  = (const float*)d_in[5];
    const float* bh0  = (const float*)d_in[6];
    const float* w1   = (const float*)d_in[7];
    // d_in[8] = w_hh_1: dead
    const float* bi1  = (const float*)d_in[9];
    const float* bh1  = (const float*)d_in[10];
    const float* wc   = (const float*)d_in[11];
    const float* bc   = (const float*)d_in[12];
    float* out = (float*)d_out;
    float* ws  = (float*)d_ws;

    // Size the cooperative grid with the runtime's own occupancy number so the
    // validation check cannot fail (R2 lesson: hand-computed capacity was rejected).
    int dev = 0;
    (void)hipGetDevice(&dev);
    int numCU = 0;
    (void)hipDeviceGetAttribute(&numCU, hipDeviceAttributeMultiprocessorCount, dev);
    int occ = 0;
    hipError_t oe = hipOccupancyMaxActiveBlocksPerMultiprocessor(&occ, fused_kernel, 256, 0);

    int maxBlocks = (oe == hipSuccess && numCU > 0) ? occ * numCU : 0;
    int gridBlocks = maxBlocks < 512 ? maxBlocks : 512;

    if (gridBlocks >= 128) {
        void* args[] = {(void*)&idx, (void*)&task, (void*)&emb,
                        (void*)&w0, (void*)&bi0, (void*)&bh0,
                        (void*)&w1, (void*)&bi1, (void*)&bh1,
                        (void*)&wc, (void*)&bc, (void*)&out, (void*)&ws};
        hipError_t le = hipLaunchCooperativeKernel(fused_kernel, dim3(gridBlocks),
                                                   dim3(256), args, 0, stream);
        if (le == hipSuccess) return;
    }

    // deterministic fallback: proven 3-kernel path
    float* h0 = ws;
    float* h1 = ws + H;
    lstm_layer_kernel<<<H, 192, 0, stream>>>(w0, bi0, bh0, emb, idx, h0);
    lstm_layer_kernel<<<H, 192, 0, stream>>>(w1, bi1, bh1, h0, nullptr, h1);
    logits_kernel<<<CH, 64, 0, stream>>>(wc, bc, h1, task, out);
}

// Round 4
// 84.740 us; speedup vs baseline: 1.0625x; 1.0625x over previous
//
#include <hip/hip_runtime.h>

#define H 2048
#define CH 19

__device__ __forceinline__ float wred(float s) {
    #pragma unroll
    for (int off = 32; off; off >>= 1) s += __shfl_down(s, off, 64);
    return s;
}

__device__ __forceinline__ float dot_row(const float* __restrict__ rowp,
                                         const float* __restrict__ xp, int lane) {
    const float4* row = (const float4*)rowp;
    const float4* x   = (const float4*)xp;
    float s = 0.f;
    #pragma unroll
    for (int j = 0; j < 8; ++j) {
        float4 w = row[lane + j * 64];
        float4 v = x[lane + j * 64];
        s += w.x * v.x + w.y * v.y + w.z * v.z + w.w * v.w;
    }
    return s;
}

__device__ __forceinline__ float sigm(float v) { return 1.f / (1.f + expf(-v)); }

// Zero initial state => w_hh matmul dead, f-gate dead.
// One block (3 waves) per hidden unit: wave0 -> gate i, wave1 -> g, wave2 -> o.
__global__ __launch_bounds__(192) void layer0_kernel(
    const float* __restrict__ w_ih, const float* __restrict__ b_ih,
    const float* __restrict__ b_hh,
    const float* __restrict__ emb, const int* __restrict__ idxp,
    float* __restrict__ h_out, unsigned* __restrict__ counter)
{
    if (blockIdx.x == 0 && threadIdx.x == 0) *counter = 0u;  // reset for layer1's last-block detect

    const int unit = blockIdx.x;
    const int wave = threadIdx.x >> 6;
    const int lane = threadIdx.x & 63;
    const int row  = (wave == 0) ? unit : (wave == 1 ? 2 * H + unit : 3 * H + unit);

    const float* x = emb + (size_t)idxp[0] * H;
    float sum = wred(dot_row(w_ih + (size_t)row * H, x, lane));

    __shared__ float g[3];
    if (lane == 0) g[wave] = sum + b_ih[row] + b_hh[row];
    __syncthreads();
    if (threadIdx.x == 0) {
        float si = sigm(g[0]);
        float so = sigm(g[2]);
        h_out[unit] = so * tanhf(si * tanhf(g[1]));
    }
}

// Layer 1 + fused logits: the last block to finish computes the 19 masked logits.
__global__ __launch_bounds__(192) void layer1_logits_kernel(
    const float* __restrict__ w_ih, const float* __restrict__ b_ih,
    const float* __restrict__ b_hh,
    const float* __restrict__ h_in,
    const float* __restrict__ wc, const float* __restrict__ bc,
    const int* __restrict__ taskp,
    float* __restrict__ h1, float* __restrict__ out,
    unsigned* __restrict__ counter)
{
    const int unit = blockIdx.x;
    const int wave = threadIdx.x >> 6;
    const int lane = threadIdx.x & 63;
    const int row  = (wave == 0) ? unit : (wave == 1 ? 2 * H + unit : 3 * H + unit);

    float sum = wred(dot_row(w_ih + (size_t)row * H, h_in, lane));

    __shared__ float g[3];
    __shared__ int is_last;
    if (lane == 0) g[wave] = sum + b_ih[row] + b_hh[row];
    __syncthreads();
    if (threadIdx.x == 0) {
        float si = sigm(g[0]);
        float so = sigm(g[2]);
        h1[unit] = so * tanhf(si * tanhf(g[1]));
        __threadfence();                         // release h1[unit] device-wide (L2 -> coherence point)
        unsigned ret = atomicAdd(counter, 1u);   // device-scope
        is_last = (ret == (unsigned)gridDim.x - 1u);
    }
    __syncthreads();

    if (is_last) {
        __threadfence();                         // acquire side before reading other blocks' h1
        // 19 logit rows over 3 waves; h1 is 8 KB, L2-resident by now.
        for (int r = wave; r < CH; r += 3) {
            float s = wred(dot_row(wc + (size_t)r * H, h1, lane));
            if (lane == 0) {
                int task = taskp[0];
                out[r] = (r < 1 + task) ? (s + bc[r]) : -1e9f;
            }
        }
    }
}

extern "C" void kernel_launch(void* const* d_in, const int* in_sizes, int n_in,
                              void* d_out, int out_size, void* d_ws, size_t ws_size,
                              hipStream_t stream) {
    const int*   idx  = (const int*)d_in[0];
    const int*   task = (const int*)d_in[1];
    const float* emb  = (const float*)d_in[2];
    const float* w0   = (const float*)d_in[3];
    // d_in[4] = w_hh_0: dead (h == 0)
    const float* bi0  = (const float*)d_in[5];
    const float* bh0  = (const float*)d_in[6];
    const float* w1   = (const float*)d_in[7];
    // d_in[8] = w_hh_1: dead
    const float* bi1  = (const float*)d_in[9];
    const float* bh1  = (const float*)d_in[10];
    const float* wc   = (const float*)d_in[11];
    const float* bc   = (const float*)d_in[12];
    float* out = (float*)d_out;
    float* ws  = (float*)d_ws;

    float*    h0      = ws;                       // [H]
    float*    h1      = ws + H;                   // [H]
    unsigned* counter = (unsigned*)(ws + 2 * H);  // [1]

    layer0_kernel<<<H, 192, 0, stream>>>(w0, bi0, bh0, emb, idx, h0, counter);
    layer1_logits_kernel<<<H, 192, 0, stream>>>(w1, bi1, bh1, h0, wc, bc, task,
                                                h1, out, counter);
}

// Round 5
// 25.924 us; speedup vs baseline: 3.4731x; 3.2687x over previous
//
#include <hip/hip_runtime.h>

#define H 2048
#define CH 19

__device__ __forceinline__ float wred(float s) {
    #pragma unroll
    for (int off = 32; off; off >>= 1) s += __shfl_down(s, off, 64);
    return s;
}

__device__ __forceinline__ float dot_row(const float* __restrict__ rowp,
                                         const float* __restrict__ xp, int lane) {
    const float4* row = (const float4*)rowp;
    const float4* x   = (const float4*)xp;
    float s = 0.f;
    #pragma unroll
    for (int j = 0; j < 8; ++j) {
        float4 w = row[lane + j * 64];
        float4 v = x[lane + j * 64];
        s += w.x * v.x + w.y * v.y + w.z * v.z + w.w * v.w;
    }
    return s;
}

__device__ __forceinline__ float sigm(float v) { return 1.f / (1.f + expf(-v)); }

// Zero initial state => w_hh matmul dead (h==0), f-gate dead (c==0).
// One block (3 waves) per hidden unit: wave0 -> gate i, wave1 -> g, wave2 -> o.
// 2048 blocks x 192 thr = 24 waves/CU, each wave streams one 8 KB row with
// 8 outstanding float4 loads -> BW-bound (proven 25.8 us total in R1).
__global__ __launch_bounds__(192) void lstm_layer_kernel(
    const float* __restrict__ w_ih, const float* __restrict__ b_ih,
    const float* __restrict__ b_hh,
    const float* __restrict__ x_base, const int* __restrict__ idx_ptr,
    float* __restrict__ h_out)
{
    const int unit = blockIdx.x;
    const int wave = threadIdx.x >> 6;
    const int lane = threadIdx.x & 63;
    const int row  = (wave == 0) ? unit : (wave == 1 ? 2 * H + unit : 3 * H + unit);

    // uniform-per-wave scalar loads: issue before the vector stream
    const float* x = x_base + (idx_ptr ? (size_t)idx_ptr[0] * H : 0);
    const float bsum = b_ih[row] + b_hh[row];

    float sum = wred(dot_row(w_ih + (size_t)row * H, x, lane));

    __shared__ float g[3];
    if (lane == 0) g[wave] = sum + bsum;
    __syncthreads();
    if (threadIdx.x == 0) {
        float si = sigm(g[0]);
        float so = sigm(g[2]);
        h_out[unit] = so * tanhf(si * tanhf(g[1]));
    }
}

// 19 blocks x 256 thr (4 waves): each lane 2 float4, wave partials via LDS.
__global__ __launch_bounds__(256) void logits_kernel(
    const float* __restrict__ wc, const float* __restrict__ bc,
    const float* __restrict__ h, const int* __restrict__ taskp,
    float* __restrict__ out)
{
    const int r = blockIdx.x;
    const int t = threadIdx.x;
    const int task = taskp[0];            // scalar, issue first
    const float4* wrow = (const float4*)(wc + (size_t)r * H);
    const float4* hv   = (const float4*)h;

    float s = 0.f;
    #pragma unroll
    for (int j = 0; j < 2; ++j) {
        int k = t + j * 256;
        float4 w = wrow[k];
        float4 v = hv[k];
        s += w.x * v.x + w.y * v.y + w.z * v.z + w.w * v.w;
    }
    s = wred(s);

    __shared__ float p[4];
    if ((t & 63) == 0) p[t >> 6] = s;
    __syncthreads();
    if (t == 0) {
        float v = p[0] + p[1] + p[2] + p[3] + bc[r];
        out[r] = (r < 1 + task) ? v : -1e9f;
    }
}

extern "C" void kernel_launch(void* const* d_in, const int* in_sizes, int n_in,
                              void* d_out, int out_size, void* d_ws, size_t ws_size,
                              hipStream_t stream) {
    const int*   idx  = (const int*)d_in[0];
    const int*   task = (const int*)d_in[1];
    const float* emb  = (const float*)d_in[2];
    const float* w0   = (const float*)d_in[3];
    // d_in[4] = w_hh_0: dead (h == 0)
    const float* bi0  = (const float*)d_in[5];
    const float* bh0  = (const float*)d_in[6];
    const float* w1   = (const float*)d_in[7];
    // d_in[8] = w_hh_1: dead
    const float* bi1  = (const float*)d_in[9];
    const float* bh1  = (const float*)d_in[10];
    const float* wc   = (const float*)d_in[11];
    const float* bc   = (const float*)d_in[12];
    float* out = (float*)d_out;
    float* ws  = (float*)d_ws;

    float* h0 = ws;
    float* h1 = ws + H;

    lstm_layer_kernel<<<H, 192, 0, stream>>>(w0, bi0, bh0, emb, idx, h0);
    lstm_layer_kernel<<<H, 192, 0, stream>>>(w1, bi1, bh1, h0, nullptr, h1);
    logits_kernel<<<CH, 256, 0, stream>>>(wc, bc, h1, task, out);
}

// Round 6
// 25.376 us; speedup vs baseline: 3.5481x; 1.0216x over previous
//
#include <hip/hip_runtime.h>

#define H 2048
#define CH 19

typedef float f32x4 __attribute__((ext_vector_type(4)));

__device__ __forceinline__ float wred(float s) {
    #pragma unroll
    for (int off = 32; off; off >>= 1) s += __shfl_down(s, off, 64);
    return s;
}

__device__ __forceinline__ float sigm(float v) { return 1.f / (1.f + expf(-v)); }

// 8-deep pipelined dot: all 16 loads issued before the FMA chain.
// Weights are read-once -> nontemporal (bypass L2 pollution); x is reused by
// every wave on the CU -> normal cached load.
__device__ __forceinline__ float dot_row_nt(const float* __restrict__ rowp,
                                            const float* __restrict__ xp, int lane) {
    const f32x4* row = (const f32x4*)rowp;
    const f32x4* x   = (const f32x4*)xp;
    f32x4 w[8], v[8];
    #pragma unroll
    for (int j = 0; j < 8; ++j) w[j] = __builtin_nontemporal_load(&row[lane + j * 64]);
    #pragma unroll
    for (int j = 0; j < 8; ++j) v[j] = x[lane + j * 64];
    float s = 0.f;
    #pragma unroll
    for (int j = 0; j < 8; ++j)
        s += w[j].x * v[j].x + w[j].y * v[j].y + w[j].z * v[j].z + w[j].w * v[j].w;
    return s;
}

// Zero initial state => w_hh matmul dead (h==0), f-gate dead (c==0).
// One block (3 waves) per hidden unit: wave0 -> gate i, wave1 -> g, wave2 -> o.
// 2048 blocks = 8 blocks/CU resident = 24 waves/CU; __launch_bounds__(192,6)
// pins VGPR <= 85 so that occupancy holds with the 8-deep load pipeline (~75 VGPR).
__global__ __launch_bounds__(192, 6) void lstm_layer_kernel(
    const float* __restrict__ w_ih, const float* __restrict__ b_ih,
    const float* __restrict__ b_hh,
    const float* __restrict__ x_base, const int* __restrict__ idx_ptr,
    float* __restrict__ h_out)
{
    const int unit = blockIdx.x;
    const int wave = threadIdx.x >> 6;
    const int lane = threadIdx.x & 63;
    const int row  = (wave == 0) ? unit : (wave == 1 ? 2 * H + unit : 3 * H + unit);

    const float* x = x_base + (idx_ptr ? (size_t)idx_ptr[0] * H : 0);
    const float bsum = b_ih[row] + b_hh[row];

    float sum = wred(dot_row_nt(w_ih + (size_t)row * H, x, lane));

    __shared__ float g[3];
    if (lane == 0) g[wave] = sum + bsum;
    __syncthreads();
    if (threadIdx.x == 0) {
        float si = sigm(g[0]);
        float so = sigm(g[2]);
        h_out[unit] = so * tanhf(si * tanhf(g[1]));
    }
}

// 19 blocks x 1 wave: no LDS, no syncthreads -> minimal latency tail.
__global__ __launch_bounds__(64) void logits_kernel(
    const float* __restrict__ wc, const float* __restrict__ bc,
    const float* __restrict__ h, const int* __restrict__ taskp,
    float* __restrict__ out)
{
    const int r = blockIdx.x;
    const int lane = threadIdx.x;
    const int task = taskp[0];
    float s = wred(dot_row_nt(wc + (size_t)r * H, h, lane));
    if (lane == 0)
        out[r] = (r < 1 + task) ? (s + bc[r]) : -1e9f;
}

extern "C" void kernel_launch(void* const* d_in, const int* in_sizes, int n_in,
                              void* d_out, int out_size, void* d_ws, size_t ws_size,
                              hipStream_t stream) {
    const int*   idx  = (const int*)d_in[0];
    const int*   task = (const int*)d_in[1];
    const float* emb  = (const float*)d_in[2];
    const float* w0   = (const float*)d_in[3];
    // d_in[4] = w_hh_0: dead (h == 0)
    const float* bi0  = (const float*)d_in[5];
    const float* bh0  = (const float*)d_in[6];
    const float* w1   = (const float*)d_in[7];
    // d_in[8] = w_hh_1: dead
    const float* bi1  = (const float*)d_in[9];
    const float* bh1  = (const float*)d_in[10];
    const float* wc   = (const float*)d_in[11];
    const float* bc   = (const float*)d_in[12];
    float* out = (float*)d_out;
    float* ws  = (float*)d_ws;

    float* h0 = ws;
    float* h1 = ws + H;

    lstm_layer_kernel<<<H, 192, 0, stream>>>(w0, bi0, bh0, emb, idx, h0);
    lstm_layer_kernel<<<H, 192, 0, stream>>>(w1, bi1, bh1, h0, nullptr, h1);
    logits_kernel<<<CH, 64, 0, stream>>>(wc, bc, h1, task, out);
}

// Round 7
// 25.120 us; speedup vs baseline: 3.5843x; 1.0102x over previous
//
#include <hip/hip_runtime.h>

#define H 2048
#define CH 19
#define SENT 0xFFFFFFFFu  // negative NaN bit pattern: h1 = sigm*tanh can never produce it

typedef float f32x4 __attribute__((ext_vector_type(4)));

__device__ __forceinline__ float wred(float s) {
    #pragma unroll
    for (int off = 32; off; off >>= 1) s += __shfl_down(s, off, 64);
    return s;
}

__device__ __forceinline__ float sigm(float v) { return 1.f / (1.f + expf(-v)); }

// 8-deep pipelined dot; weights are read-once -> nontemporal.
__device__ __forceinline__ float dot_row_nt(const float* __restrict__ rowp,
                                            const float* __restrict__ xp, int lane) {
    const f32x4* row = (const f32x4*)rowp;
    const f32x4* x   = (const f32x4*)xp;
    f32x4 w[8], v[8];
    #pragma unroll
    for (int j = 0; j < 8; ++j) w[j] = __builtin_nontemporal_load(&row[lane + j * 64]);
    #pragma unroll
    for (int j = 0; j < 8; ++j) v[j] = x[lane + j * 64];
    float s = 0.f;
    #pragma unroll
    for (int j = 0; j < 8; ++j)
        s += w[j].x * v[j].x + w[j].y * v[j].y + w[j].z * v[j].z + w[j].w * v[j].w;
    return s;
}

// Layer 0: one block (3 waves) per unit. Also re-arms the h1 sentinel slots for
// this call (graph edge orders this before kernel B), keeping replays deterministic.
__global__ __launch_bounds__(192, 6) void layer0_kernel(
    const float* __restrict__ w_ih, const float* __restrict__ b_ih,
    const float* __restrict__ b_hh,
    const float* __restrict__ emb, const int* __restrict__ idxp,
    float* __restrict__ h_out, unsigned* __restrict__ h1_slots)
{
    const int unit = blockIdx.x;
    if (threadIdx.x == 0) h1_slots[unit] = SENT;

    const int wave = threadIdx.x >> 6;
    const int lane = threadIdx.x & 63;
    const int row  = (wave == 0) ? unit : (wave == 1 ? 2 * H + unit : 3 * H + unit);

    const float* x = emb + (size_t)idxp[0] * H;
    const float bsum = b_ih[row] + b_hh[row];
    float sum = wred(dot_row_nt(w_ih + (size_t)row * H, x, lane));

    __shared__ float g[3];
    if (lane == 0) g[wave] = sum + bsum;
    __syncthreads();
    if (threadIdx.x == 0) {
        float si = sigm(g[0]);
        float so = sigm(g[2]);
        h_out[unit] = so * tanhf(si * tanhf(g[1]));
    }
}

// Layer 1 + fused logits, no global barrier:
//  blocks 0..2047  (writers): compute h1[u], publish via relaxed agent-scope
//                  store to a distinct slot (distinct addresses -> no serialization).
//  blocks 2048..2066 (readers): prefetch wc row to registers, then poll slots and
//                  FMA values as they appear. Writers never wait -> no deadlock.
__global__ __launch_bounds__(192, 6) void layer1_logits_kernel(
    const float* __restrict__ w_ih, const float* __restrict__ b_ih,
    const float* __restrict__ b_hh,
    const float* __restrict__ h_in,
    const float* __restrict__ wc, const float* __restrict__ bc,
    const int* __restrict__ taskp,
    unsigned* __restrict__ h1_slots, float* __restrict__ out)
{
    if (blockIdx.x < H) {
        // ---- writer: one unit, 3 gate waves ----
        const int unit = blockIdx.x;
        const int wave = threadIdx.x >> 6;
        const int lane = threadIdx.x & 63;
        const int row  = (wave == 0) ? unit : (wave == 1 ? 2 * H + unit : 3 * H + unit);

        const float bsum = b_ih[row] + b_hh[row];
        float sum = wred(dot_row_nt(w_ih + (size_t)row * H, h_in, lane));

        __shared__ float g[3];
        if (lane == 0) g[wave] = sum + bsum;
        __syncthreads();
        if (threadIdx.x == 0) {
            float si = sigm(g[0]);
            float so = sigm(g[2]);
            float h1 = so * tanhf(si * tanhf(g[1]));
            __hip_atomic_store(&h1_slots[unit], __float_as_uint(h1),
                               __ATOMIC_RELAXED, __HIP_MEMORY_SCOPE_AGENT);
        }
    } else {
        // ---- reader: one logit row over 192 threads ----
        const int r = blockIdx.x - H;
        const int t = threadIdx.x;
        const int task = taskp[0];
        const float* wrow = wc + (size_t)r * H;

        // prefetch wc row (coalesced per k: lanes t..t+191 consecutive)
        float wcr[11];
        #pragma unroll
        for (int k = 0; k < 11; ++k) {
            int u = t + k * 192;
            wcr[k] = (u < H) ? wrow[u] : 0.f;
        }

        float s = 0.f;
        #pragma unroll
        for (int k = 0; k < 11; ++k) {
            int u = t + k * 192;
            if (u < H) {
                unsigned v;
                for (;;) {
                    v = __hip_atomic_load(&h1_slots[u], __ATOMIC_RELAXED,
                                          __HIP_MEMORY_SCOPE_AGENT);
                    if (v != SENT) break;
                    __builtin_amdgcn_s_sleep(1);
                }
                s += wcr[k] * __uint_as_float(v);
            }
        }
        s = wred(s);

        __shared__ float p[3];
        if ((t & 63) == 0) p[t >> 6] = s;
        __syncthreads();
        if (t == 0) {
            float v = p[0] + p[1] + p[2] + bc[r];
            out[r] = (r < 1 + task) ? v : -1e9f;
        }
    }
}

extern "C" void kernel_launch(void* const* d_in, const int* in_sizes, int n_in,
                              void* d_out, int out_size, void* d_ws, size_t ws_size,
                              hipStream_t stream) {
    const int*   idx  = (const int*)d_in[0];
    const int*   task = (const int*)d_in[1];
    const float* emb  = (const float*)d_in[2];
    const float* w0   = (const float*)d_in[3];
    // d_in[4] = w_hh_0: dead (h == 0)
    const float* bi0  = (const float*)d_in[5];
    const float* bh0  = (const float*)d_in[6];
    const float* w1   = (const float*)d_in[7];
    // d_in[8] = w_hh_1: dead
    const float* bi1  = (const float*)d_in[9];
    const float* bh1  = (const float*)d_in[10];
    const float* wc   = (const float*)d_in[11];
    const float* bc   = (const float*)d_in[12];
    float* out = (float*)d_out;
    float* ws  = (float*)d_ws;

    float*    h0       = ws;                      // [H]
    unsigned* h1_slots = (unsigned*)(ws + H);     // [H]

    layer0_kernel<<<H, 192, 0, stream>>>(w0, bi0, bh0, emb, idx, h0, h1_slots);
    layer1_logits_kernel<<<H + CH, 192, 0, stream>>>(w1, bi1, bh1, h0, wc, bc, task,
                                                     h1_slots, out);
}